// Round 12
// baseline (141.817 us; speedup 1.0000x reference)
//
#include <hip/hip_runtime.h>

// ChannelAttention on MI355X (gfx950) — R11: fused split-bf16 MFMA, chunked
// B=128, HW=256, C=1024, S=32, EMB=256, IDF=256(==HW)
//
// out[b,p,c] = sum_s we[b,s,p] * softmax_s( sum_p' wc[b,p',c] * we[b,s,p'] )
// attn[b,c,s] = softmax probabilities
// d_out: out (128*256*1024 f32) then attn (128*1024*32 f32); d_ws unused.
//
// R11 = R9 base (83us, 4 waves x 64c, 2 blocks/CU) with the wave's work
// split into 4 chunks of 16 c: fetch(A) -> softmax -> write(B) per chunk,
// next chunk's 64 wc dwords issued BEFORE computing the current chunk
// (cover = A+sm+B ~ 3000 cyc >> 900 HBM). Chunk 0 issued before the
// projection. This interleaves the HBM read and write streams (R9 ran
// all-fetch then all-write, serializing the two ~21us/CU streams) and
// removes phase-A's exposed latency (R9 prefetch was 1 m-step ~150 cyc).
// R10 lesson: occupancy is NOT the lever (2x waves/SIMD regressed); revert
// to 256 thr, launch_bounds(256,2) so VGPR (~180 for w[2][64]) is free.
// MFMA layouts (R8/R9 HW-verified):
//   A[M][K]: row=l&15, k=(l>>4)*8+i ; B[K][N]: col=l&15, same k
//   C/D: col=l&15, row=(l>>4)*4+reg

typedef float  f32x4  __attribute__((ext_vector_type(4)));
typedef short  bf16x8 __attribute__((ext_vector_type(8)));

namespace {
constexpr int kB = 128, kHW = 256, kC = 1024, kS = 32, kE = 256;
constexpr int TP = kHW + 8;  // 264 u16 row stride
constexpr int WR = kS + 8;   // 40 u16 row stride
}

__device__ inline ushort f2bf(float x) {             // f32 -> bf16 RNE
  unsigned u = __float_as_uint(x);
  u += 0x7fffu + ((u >> 16) & 1u);
  return (ushort)(u >> 16);
}
__device__ inline float bf2f(ushort h) { return __uint_as_float(((unsigned)h) << 16); }

#define MFMA16(A, Bf, Cv) __builtin_amdgcn_mfma_f32_16x16x32_bf16((A), (Bf), (Cv), 0, 0, 0)

// grid (4,128), 256 thr = 4 waves; block: one b, 256 channels; wave: 64 c.
__global__ __launch_bounds__(256, 2) void fused_attn_kernel(
    const float* __restrict__ wc, const float* __restrict__ emb,
    const float* __restrict__ Km, const float* __restrict__ bias,
    float* __restrict__ out, float* __restrict__ attn_out) {
  const int b    = blockIdx.y;
  const int cb   = blockIdx.x * 256;
  const int tid  = threadIdx.x;
  const int wave = tid >> 6, lane = tid & 63;
  const int lr   = lane & 15, lg = lane >> 4;

  __shared__ ushort wHT[kS][TP];    // weT^T hi [s][p]
  __shared__ ushort wLT[kS][TP];    // weT^T lo [s][p]
  __shared__ ushort wHp[kHW][WR];   // weT  hi  [p][s]
  __shared__ ushort pHl[kHW][WR];   // P    hi  [c][s]

  const float* wcb = wc + (size_t)b * kHW * kC;
  const int c0 = cb + wave * 64;

  // ---- chunk 0 wc loads issued first; latency hides under projection ----
  float w[2][64];
#pragma unroll
  for (int kt = 0; kt < 8; ++kt)
#pragma unroll
    for (int i = 0; i < 8; ++i)
      w[0][kt * 8 + i] = wcb[(size_t)(kt * 32 + lg * 8 + i) * kC + c0 + lr];

  // ================= projection: weT[s][p] = emb x K (R9 verbatim) =======
  {
    const float* embb = emb + (size_t)b * kS * kE;
    f32x4 pcc[2][4];
#pragma unroll
    for (int m = 0; m < 2; ++m)
#pragma unroll
      for (int n = 0; n < 4; ++n) pcc[m][n] = (f32x4){0.f, 0.f, 0.f, 0.f};

#pragma unroll 1
    for (int kt = 0; kt < 8; ++kt) {
      bf16x8 eah[2], eal[2];
#pragma unroll
      for (int m = 0; m < 2; ++m) {
        const float* ep = embb + (size_t)(m * 16 + lr) * kE + kt * 32 + lg * 8;
        const float4 v0 = *(const float4*)ep;
        const float4 v1 = *(const float4*)(ep + 4);
        const float ev[8] = {v0.x, v0.y, v0.z, v0.w, v1.x, v1.y, v1.z, v1.w};
#pragma unroll
        for (int i = 0; i < 8; ++i) {
          const ushort h = f2bf(ev[i]);
          eah[m][i] = (short)h;
          eal[m][i] = (short)f2bf(ev[i] - bf2f(h));
        }
      }
#pragma unroll
      for (int n = 0; n < 4; ++n) {
        const int pg = wave * 64 + n * 16 + lr;
        bf16x8 kh, kl;
#pragma unroll
        for (int i = 0; i < 8; ++i) {
          const float kv = Km[(size_t)(kt * 32 + lg * 8 + i) * kHW + pg];
          const ushort h = f2bf(kv);
          kh[i] = (short)h;
          kl[i] = (short)f2bf(kv - bf2f(h));
        }
#pragma unroll
        for (int m = 0; m < 2; ++m) {
          pcc[m][n] = MFMA16(eah[m], kh, pcc[m][n]);
          pcc[m][n] = MFMA16(eah[m], kl, pcc[m][n]);
          pcc[m][n] = MFMA16(eal[m], kh, pcc[m][n]);
        }
      }
    }
#pragma unroll
    for (int n = 0; n < 4; ++n) {
      const int pg = wave * 64 + n * 16 + lr;
      const float bv = bias[pg];
#pragma unroll
      for (int m = 0; m < 2; ++m)
#pragma unroll
        for (int j = 0; j < 4; ++j) {
          const float x = pcc[m][n][j] + bv;
          const ushort h = f2bf(x);
          const int s = m * 16 + lg * 4 + j;
          wHT[s][pg] = h;
          wLT[s][pg] = (ushort)f2bf(x - bf2f(h));
          wHp[pg][s] = h;
        }
    }
  }
  __syncthreads();

  float* attnb = attn_out + ((size_t)b * kC + cb) * kS;
  float* outb  = out + (size_t)b * kHW * kC + cb;

  // ======= chunk loop: 4 x (16 c) — fetch / compute / write interleaved ===
#pragma unroll
  for (int m = 0; m < 4; ++m) {
    const int cur = m & 1, nxt = cur ^ 1;

    // issue next chunk's wc loads (consumed one full chunk later)
    if (m < 3) {
#pragma unroll
      for (int kt = 0; kt < 8; ++kt)
#pragma unroll
        for (int i = 0; i < 8; ++i)
          w[nxt][kt * 8 + i] =
              wcb[(size_t)(kt * 32 + lg * 8 + i) * kC + c0 + (m + 1) * 16 + lr];
    }

    // ---- Phase A: D[c][s] for this chunk's 16 c; K=256 ----
    f32x4 acc0 = (f32x4){0.f, 0.f, 0.f, 0.f};
    f32x4 acc1 = (f32x4){0.f, 0.f, 0.f, 0.f};
#pragma unroll
    for (int kt = 0; kt < 8; ++kt) {
      const bf16x8 bh0 = *(const bf16x8*)&wHT[lr][kt * 32 + lg * 8];
      const bf16x8 bl0 = *(const bf16x8*)&wLT[lr][kt * 32 + lg * 8];
      const bf16x8 bh1 = *(const bf16x8*)&wHT[16 + lr][kt * 32 + lg * 8];
      const bf16x8 bl1 = *(const bf16x8*)&wLT[16 + lr][kt * 32 + lg * 8];
      bf16x8 ah, al;
#pragma unroll
      for (int i = 0; i < 8; ++i) {
        const float v = w[cur][kt * 8 + i];
        const ushort h = f2bf(v);
        ah[i] = (short)h;
        al[i] = (short)f2bf(v - bf2f(h));
      }
      acc0 = MFMA16(ah, bh0, acc0);
      acc0 = MFMA16(ah, bl0, acc0);
      acc0 = MFMA16(al, bh0, acc0);
      acc1 = MFMA16(ah, bh1, acc1);
      acc1 = MFMA16(ah, bl1, acc1);
      acc1 = MFMA16(al, bh1, acc1);
    }

    // ---- softmax over s (rows c = c0+m*16+lg*4+j; cols s=lr, 16+lr) ----
#pragma unroll
    for (int j = 0; j < 4; ++j) {
      float v0 = acc0[j], v1 = acc1[j];
      float mx = fmaxf(v0, v1);
      mx = fmaxf(mx, __shfl_xor(mx, 1));
      mx = fmaxf(mx, __shfl_xor(mx, 2));
      mx = fmaxf(mx, __shfl_xor(mx, 4));
      mx = fmaxf(mx, __shfl_xor(mx, 8));
      float e0 = __expf(v0 - mx), e1 = __expf(v1 - mx);
      float sm = e0 + e1;
      sm += __shfl_xor(sm, 1); sm += __shfl_xor(sm, 2);
      sm += __shfl_xor(sm, 4); sm += __shfl_xor(sm, 8);
      const float inv = 1.f / sm;
      e0 *= inv; e1 *= inv;
      const int cL = wave * 64 + m * 16 + lg * 4 + j;
      attnb[(size_t)cL * kS + lr]      = e0;
      attnb[(size_t)cL * kS + 16 + lr] = e1;
      pHl[cL][lr]      = f2bf(e0);
      pHl[cL][16 + lr] = f2bf(e1);
    }
    // P rows are wave-local: no barrier.

    // ---- Phase B: D[p][c-chunk] = weT(hi) x P(hi); K=32, 16 p-tiles ----
    const bf16x8 pb = *(const bf16x8*)&pHl[wave * 64 + m * 16 + lr][lg * 8];
    const int ccol = wave * 64 + m * 16 + lr;
#pragma unroll 1
    for (int pt = 0; pt < 16; ++pt) {
      const bf16x8 ah = *(const bf16x8*)&wHp[pt * 16 + lr][lg * 8];
      f32x4 o = (f32x4){0.f, 0.f, 0.f, 0.f};
      o = MFMA16(ah, pb, o);
#pragma unroll
      for (int j = 0; j < 4; ++j)
        outb[(size_t)(pt * 16 + lg * 4 + j) * kC + ccol] = o[j];
    }
  }
}

extern "C" void kernel_launch(void* const* d_in, const int* in_sizes, int n_in,
                              void* d_out, int out_size, void* d_ws, size_t ws_size,
                              hipStream_t stream) {
  const float* wc   = (const float*)d_in[0];
  const float* emb  = (const float*)d_in[1];
  const float* Km   = (const float*)d_in[2];
  const float* bias = (const float*)d_in[3];

  float* out  = (float*)d_out;
  float* attn = out + (size_t)kB * kHW * kC;

  fused_attn_kernel<<<dim3(4, kB), 256, 0, stream>>>(wc, emb, Km, bias, out, attn);
}

// Round 13
// 102.302 us; speedup vs baseline: 1.3863x; 1.3863x over previous
//
#include <hip/hip_runtime.h>

// ChannelAttention on MI355X (gfx950) — R12: R9 + per-chunk phase interleave
// B=128, HW=256, C=1024, S=32, EMB=256, IDF=256(==HW)
//
// out[b,p,c] = sum_s we[b,s,p] * softmax_s( sum_p' wc[b,p',c] * we[b,s,p'] )
// attn[b,c,s] = softmax probabilities
// d_out: out (128*256*1024 f32) then attn (128*1024*32 f32); d_ws unused.
//
// R12 = R9 (83us, proven) with phase B moved INSIDE the m-loop:
//   per 16-c chunk m: A(m, 8-reg kt ping-pong) -> issue next-m kt0 loads
//   (cover = softmax+B ~1200cyc >= L3 ~350cyc) -> softmax(m) -> B(m) stores.
// Interleaves the HBM read stream (A) with the write stream (B) at ~1.5us
// granularity instead of all-fetch-then-all-write per block (R8/R9's shared
// 83us wall), and closes R9's 150cyc cross-m prefetch gap.
// R11 lesson: same idea with w[2][64] chunk buffers spilled to scratch
// (FETCH 77->158MB); here register state stays R9's 8+8 ping-pong. m-loop
// rolled (unroll 1) -> static reg indexing, ~8KB body.
// MFMA layouts (R8/R9 HW-verified):
//   A[M][K]: row=l&15, k=(l>>4)*8+i ; B[K][N]: col=l&15, same k
//   C/D: col=l&15, row=(l>>4)*4+reg

typedef float  f32x4  __attribute__((ext_vector_type(4)));
typedef short  bf16x8 __attribute__((ext_vector_type(8)));

namespace {
constexpr int kB = 128, kHW = 256, kC = 1024, kS = 32, kE = 256;
constexpr int TP = kHW + 8;  // 264 u16 row stride (528B, 16B-mult)
constexpr int WR = kS + 8;   // 40 u16 row stride (80B, 16B-mult)
}

__device__ inline ushort f2bf(float x) {             // f32 -> bf16 RNE
  unsigned u = __float_as_uint(x);
  u += 0x7fffu + ((u >> 16) & 1u);
  return (ushort)(u >> 16);
}
__device__ inline float bf2f(ushort h) { return __uint_as_float(((unsigned)h) << 16); }

#define MFMA16(A, Bf, Cv) __builtin_amdgcn_mfma_f32_16x16x32_bf16((A), (Bf), (Cv), 0, 0, 0)

// grid (4,128), 256 thr = 4 waves; block: one b, 256 channels; wave: 64 c.
__global__ __launch_bounds__(256, 2) void fused_attn_kernel(
    const float* __restrict__ wc, const float* __restrict__ emb,
    const float* __restrict__ Km, const float* __restrict__ bias,
    float* __restrict__ out, float* __restrict__ attn_out) {
  const int b    = blockIdx.y;
  const int cb   = blockIdx.x * 256;
  const int tid  = threadIdx.x;
  const int wave = tid >> 6, lane = tid & 63;
  const int lr   = lane & 15, lg = lane >> 4;

  __shared__ ushort wHT[kS][TP];    // weT^T hi [s][p]
  __shared__ ushort wLT[kS][TP];    // weT^T lo [s][p]
  __shared__ ushort wHp[kHW][WR];   // weT  hi  [p][s]
  __shared__ ushort pHl[kHW][WR];   // P    hi  [c][s]

  const float* wcb = wc + (size_t)b * kHW * kC;
  const int c0 = cb + wave * 64;

  // ---- chunk-0 kt=0 wc loads issued first; hide under projection ----
  float avC[8], avN[8];
#pragma unroll
  for (int i = 0; i < 8; ++i)
    avC[i] = wcb[(size_t)(lg * 8 + i) * kC + c0 + lr];

  // ================= projection: weT[s][p] = emb x K (R9 verbatim) =======
  {
    const float* embb = emb + (size_t)b * kS * kE;
    f32x4 pcc[2][4];
#pragma unroll
    for (int m = 0; m < 2; ++m)
#pragma unroll
      for (int n = 0; n < 4; ++n) pcc[m][n] = (f32x4){0.f, 0.f, 0.f, 0.f};

#pragma unroll 1
    for (int kt = 0; kt < 8; ++kt) {
      bf16x8 eah[2], eal[2];
#pragma unroll
      for (int m = 0; m < 2; ++m) {
        const float* ep = embb + (size_t)(m * 16 + lr) * kE + kt * 32 + lg * 8;
        const float4 v0 = *(const float4*)ep;
        const float4 v1 = *(const float4*)(ep + 4);
        const float ev[8] = {v0.x, v0.y, v0.z, v0.w, v1.x, v1.y, v1.z, v1.w};
#pragma unroll
        for (int i = 0; i < 8; ++i) {
          const ushort h = f2bf(ev[i]);
          eah[m][i] = (short)h;
          eal[m][i] = (short)f2bf(ev[i] - bf2f(h));
        }
      }
#pragma unroll
      for (int n = 0; n < 4; ++n) {
        const int pg = wave * 64 + n * 16 + lr;
        bf16x8 kh, kl;
#pragma unroll
        for (int i = 0; i < 8; ++i) {
          const float kv = Km[(size_t)(kt * 32 + lg * 8 + i) * kHW + pg];
          const ushort h = f2bf(kv);
          kh[i] = (short)h;
          kl[i] = (short)f2bf(kv - bf2f(h));
        }
#pragma unroll
        for (int m = 0; m < 2; ++m) {
          pcc[m][n] = MFMA16(eah[m], kh, pcc[m][n]);
          pcc[m][n] = MFMA16(eah[m], kl, pcc[m][n]);
          pcc[m][n] = MFMA16(eal[m], kh, pcc[m][n]);
        }
      }
    }
#pragma unroll
    for (int n = 0; n < 4; ++n) {
      const int pg = wave * 64 + n * 16 + lr;
      const float bv = bias[pg];
#pragma unroll
      for (int m = 0; m < 2; ++m)
#pragma unroll
        for (int j = 0; j < 4; ++j) {
          const float x = pcc[m][n][j] + bv;
          const ushort h = f2bf(x);
          const int s = m * 16 + lg * 4 + j;
          wHT[s][pg] = h;
          wLT[s][pg] = (ushort)f2bf(x - bf2f(h));
          wHp[pg][s] = h;
        }
    }
  }
  __syncthreads();

  float* attnb = attn_out + ((size_t)b * kC + cb) * kS;
  float* outb  = out + (size_t)b * kHW * kC + cb;

  // ======= chunk loop: 4 x (16 c) — A / prefetch-next / softmax / B =======
#pragma unroll 1
  for (int m = 0; m < 4; ++m) {
    // ---- Phase A(m): D[c][s], K=256, kt ping-pong (avC preloaded) ----
    f32x4 acc0 = (f32x4){0.f, 0.f, 0.f, 0.f};
    f32x4 acc1 = (f32x4){0.f, 0.f, 0.f, 0.f};
#pragma unroll
    for (int kt = 0; kt < 8; ++kt) {
      const bf16x8 bh0 = *(const bf16x8*)&wHT[lr][kt * 32 + lg * 8];
      const bf16x8 bl0 = *(const bf16x8*)&wLT[lr][kt * 32 + lg * 8];
      const bf16x8 bh1 = *(const bf16x8*)&wHT[16 + lr][kt * 32 + lg * 8];
      const bf16x8 bl1 = *(const bf16x8*)&wLT[16 + lr][kt * 32 + lg * 8];
      if (kt < 7) {
#pragma unroll
        for (int i = 0; i < 8; ++i)
          avN[i] = wcb[(size_t)((kt + 1) * 32 + lg * 8 + i) * kC + c0 + m * 16 + lr];
      }
      bf16x8 ah, al;
#pragma unroll
      for (int i = 0; i < 8; ++i) {
        const ushort h = f2bf(avC[i]);
        ah[i] = (short)h;
        al[i] = (short)f2bf(avC[i] - bf2f(h));
      }
      acc0 = MFMA16(ah, bh0, acc0);
      acc0 = MFMA16(ah, bl0, acc0);
      acc0 = MFMA16(al, bh0, acc0);
      acc1 = MFMA16(ah, bh1, acc1);
      acc1 = MFMA16(ah, bl1, acc1);
      acc1 = MFMA16(al, bh1, acc1);
      if (kt < 7) {
#pragma unroll
        for (int i = 0; i < 8; ++i) avC[i] = avN[i];
      }
    }

    // ---- issue next chunk's kt=0 loads; softmax+B below give cover ----
    if (m < 3) {
#pragma unroll
      for (int i = 0; i < 8; ++i)
        avN[i] = wcb[(size_t)(lg * 8 + i) * kC + c0 + (m + 1) * 16 + lr];
    }

    // ---- softmax over s (rows c = c0+m*16+lg*4+j; cols s=lr, 16+lr) ----
#pragma unroll
    for (int j = 0; j < 4; ++j) {
      float v0 = acc0[j], v1 = acc1[j];
      float mx = fmaxf(v0, v1);
      mx = fmaxf(mx, __shfl_xor(mx, 1));
      mx = fmaxf(mx, __shfl_xor(mx, 2));
      mx = fmaxf(mx, __shfl_xor(mx, 4));
      mx = fmaxf(mx, __shfl_xor(mx, 8));
      float e0 = __expf(v0 - mx), e1 = __expf(v1 - mx);
      float sm = e0 + e1;
      sm += __shfl_xor(sm, 1); sm += __shfl_xor(sm, 2);
      sm += __shfl_xor(sm, 4); sm += __shfl_xor(sm, 8);
      const float inv = 1.f / sm;
      e0 *= inv; e1 *= inv;
      const int cL = wave * 64 + m * 16 + lg * 4 + j;
      attnb[(size_t)cL * kS + lr]      = e0;
      attnb[(size_t)cL * kS + 16 + lr] = e1;
      pHl[cL][lr]      = f2bf(e0);
      pHl[cL][16 + lr] = f2bf(e1);
    }
    // P rows are wave-local: no barrier.

    // ---- Phase B(m): D[p][c-chunk] = weT(hi) x P(hi); 16 p-tiles ----
    const bf16x8 pb = *(const bf16x8*)&pHl[wave * 64 + m * 16 + lr][lg * 8];
    const int ccol = wave * 64 + m * 16 + lr;
#pragma unroll 1
    for (int pt = 0; pt < 16; ++pt) {
      const bf16x8 ah = *(const bf16x8*)&wHp[pt * 16 + lr][lg * 8];
      f32x4 o = (f32x4){0.f, 0.f, 0.f, 0.f};
      o = MFMA16(ah, pb, o);
#pragma unroll
      for (int j = 0; j < 4; ++j)
        outb[(size_t)(pt * 16 + lg * 4 + j) * kC + ccol] = o[j];
    }

    // carry next chunk's prefetch into avC
#pragma unroll
    for (int i = 0; i < 8; ++i) avC[i] = avN[i];
  }
}

extern "C" void kernel_launch(void* const* d_in, const int* in_sizes, int n_in,
                              void* d_out, int out_size, void* d_ws, size_t ws_size,
                              hipStream_t stream) {
  const float* wc   = (const float*)d_in[0];
  const float* emb  = (const float*)d_in[1];
  const float* Km   = (const float*)d_in[2];
  const float* bias = (const float*)d_in[3];

  float* out  = (float*)d_out;
  float* attn = out + (size_t)kB * kHW * kC;

  fused_attn_kernel<<<dim3(4, kB), 256, 0, stream>>>(wc, emb, Km, bias, out, attn);
}